// Round 20
// baseline (57.321 us; speedup 1.0000x reference)
//
#include <hip/hip_runtime.h>
#include <math.h>

// DRR via Siddon ray tracing, 256^3 volume, 256x256 detector.
// R18 skeleton (proven best, 54.4us) + XCD-aware block swizzle:
//  - 2048 blocks x 512 threads; wave = 64 CONSECUTIVE rays x ONE partition
//    (minimal footprint + minimal divergence); block = 64 rays x 8 partitions;
//    LDS fold of 8 waves + 1 atomicAdd per block (out zeroed by memsetAsync).
//  - XCD swizzle: launch index b goes round-robin to XCDs (b&7 = XCD id);
//    remap lb=(b&7)*256+(b>>3) so each XCD owns 256 logically-consecutive
//    blocks = 32 consecutive detector columns = one contiguous ~8MB volume
//    slab, instead of all 8 XCDs streaming the full ~40MB working set
//    through their private 4MB L2s. Pure bijective permutation (2048%8==0).
// Inner loop bit-identical to R10/R18 (midpoint-trunc cells, reference-
// faithful rounding; range-checked advance; depth-1 software pipeline).

#define NPLANE 256
constexpr int TPR = 16;

__device__ __forceinline__ float palpha(int i, float sp, float src, float rd) {
    return fmaf((float)i, sp, -src) * rd;
}

__global__ __launch_bounds__(512) void drr_kernel(
    const float* __restrict__ vol,
    const float* __restrict__ spacing,
    const float* __restrict__ sdrp,
    const float* __restrict__ rot,
    const float* __restrict__ trans,
    float* __restrict__ out)
{
    int tid  = threadIdx.x;
    int lane = tid & 63;                     // ray-in-group (fast)
    int wave = tid >> 6;                     // 0..7
    int b    = (int)blockIdx.x;
    // XCD-aware swizzle: b&7 = XCD (round-robin dispatch); give each XCD a
    // contiguous logical range so its L2 sees one volume slab.
    int lb   = ((b & 7) << 8) | (b >> 3);    // bijection on [0,2048)
    int g    = lb >> 1;                      // 64-ray group 0..1023
    int h    = lb & 1;                       // partition half
    int part = (h << 3) | wave;              // 0..15
    int rl   = (g << 6) | lane;              // 0..65535 linear ray id

    // R = Rz(theta) @ Ry(phi) @ Rx(gamma): columns 0 (ray dir), 1 (u), 2 (v)
    float theta = rot[0], phi = rot[1], gam = rot[2];
    float ct = cosf(theta), st = sinf(theta);
    float cp = cosf(phi),   sp_ = sinf(phi);
    float cg = cosf(gam),   sg = sinf(gam);

    float r0x = ct * cp, r0y = st * cp, r0z = -sp_;
    float ux = ct * sp_ * sg - st * cg, uy = st * sp_ * sg + ct * cg, uz = cp * sg;
    float vx = ct * sp_ * cg + st * sg, vy = st * sp_ * cg - ct * sg, vz = cp * cg;

    // lane-fast detector axis = least stride-weighted volume motion (uniform)
    float cost_u = fabsf(ux) * 65536.f + fabsf(uy) * 256.f + fabsf(uz);
    float cost_v = fabsf(vx) * 65536.f + fabsf(vy) * 256.f + fabsf(vz);
    bool tfast = cost_u < cost_v;
    int ti = tfast ? (rl & 255) : (rl >> 8);
    int si = tfast ? (rl >> 8) : (rl & 255);

    float sdr = sdrp[0];
    float tx = trans[0], ty = trans[1], tz = trans[2];

    float sx = sdr * r0x + tx,  sy = sdr * r0y + ty,  sz = sdr * r0z + tz;
    float cxx = -sdr * r0x + tx, cxy = -sdr * r0y + ty, cxz = -sdr * r0z + tz;

    float tval = (float)(ti - 127) * 2.0f;
    float sval = (float)(si - 127) * 2.0f;

    float gx = tval * ux + sval * vx + cxx;
    float gy = tval * uy + sval * vy + cxy;
    float gz = tval * uz + sval * vz + cxz;

    float sdx = gx - sx + 1e-8f;
    float sdy = gy - sy + 1e-8f;
    float sdz = gz - sz + 1e-8f;

    float spx = spacing[0], spy = spacing[1], spz = spacing[2];
    float rdx = 1.0f / sdx, rdy = 1.0f / sdy, rdz = 1.0f / sdz;

    float a0x = palpha(0, spx, sx, rdx), a1x = palpha(NPLANE, spx, sx, rdx);
    float a0y = palpha(0, spy, sy, rdy), a1y = palpha(NPLANE, spy, sy, rdy);
    float a0z = palpha(0, spz, sz, rdz), a1z = palpha(NPLANE, spz, sz, rdz);

    float amin = fmaxf(fmaxf(fminf(a0x, a1x), fminf(a0y, a1y)), fminf(a0z, a1z));
    float amax = fminf(fminf(fmaxf(a0x, a1x), fmaxf(a0y, a1y)), fmaxf(a0z, a1z));

    float acc = 0.f;

    if (amax > amin) {
        float range = amax - amin;
        constexpr float inv = 1.0f / (float)TPR;
        float lo = fmaf(range, (float)part * inv, amin);
        float hi = (part == TPR - 1) ? INFINITY
                                     : fmaf(range, (float)(part + 1) * inv, amin);
        float end = fminf(hi, amax);

        int ix, iy, iz, dix, diy, diz;
        float nxx, nxy, nxz;

        // first plane crossing with alpha >= lo per axis
        #define SETUP(SP, SRC, SDD, RD, I, DI, NXT)                                \
        {                                                                          \
            float q = fmaf(lo, SDD, SRC) / (SP);                                   \
            q = fminf(fmaxf(q, -1.f), 257.f);                                      \
            if ((SDD) > 0.f) {                                                     \
                DI = 1;                                                            \
                I = (int)ceilf(q);                                                 \
                while (I > 0 && palpha(I - 1, SP, SRC, RD) >= lo) --I;             \
                while (I <= NPLANE && palpha(I, SP, SRC, RD) < lo) ++I;            \
                NXT = (I <= NPLANE) ? palpha(I, SP, SRC, RD) : INFINITY;           \
            } else {                                                               \
                DI = -1;                                                           \
                I = (int)floorf(q);                                                \
                while (I < NPLANE && palpha(I + 1, SP, SRC, RD) >= lo) ++I;        \
                while (I >= 0 && palpha(I, SP, SRC, RD) < lo) --I;                 \
                NXT = (I >= 0) ? palpha(I, SP, SRC, RD) : INFINITY;                \
            }                                                                      \
        }

        SETUP(spx, sx, sdx, rdx, ix, dix, nxx)
        SETUP(spy, sy, sdy, rdy, iy, diy, nxy)
        SETUP(spz, sz, sdz, rdz, iz, diz, nxz)
        #undef SETUP

        float ispx = 1.0f / spx, ispy = 1.0f / spy, ispz = 1.0f / spz;

        #define ADVANCE_MERGE()                                                    \
            if (nxx == cur) { ix += dix;                                           \
                nxx = ((unsigned)ix <= NPLANE) ? palpha(ix, spx, sx, rdx)          \
                                               : INFINITY; }                       \
            if (nxy == cur) { iy += diy;                                           \
                nxy = ((unsigned)iy <= NPLANE) ? palpha(iy, spy, sy, rdy)          \
                                               : INFINITY; }                       \
            if (nxz == cur) { iz += diz;                                           \
                nxz = ((unsigned)iz <= NPLANE) ? palpha(iz, spz, sz, rdz)          \
                                               : INFINITY; }

        #define SEG_ADDR(CUR, E, ADDR)                                             \
        {                                                                          \
            float amid = 0.5f * ((CUR) + (E));                                     \
            float pxv = fmaf(amid, sdx, sx) * ispx;                                \
            float pyv = fmaf(amid, sdy, sy) * ispy;                                \
            float pzv = fmaf(amid, sdz, sz) * ispz;                                \
            int jx = (int)pxv; jx = jx < 0 ? 0 : (jx > 255 ? 255 : jx);            \
            int jy = (int)pyv; jy = jy < 0 ? 0 : (jy > 255 ? 255 : jy);            \
            int jz = (int)pzv; jz = jz < 0 ? 0 : (jz > 255 ? 255 : jz);            \
            ADDR = (jx << 16) + (jy << 8) + jz;                                    \
        }

        float cur = fminf(fminf(nxx, nxy), nxz);

        if (cur < end) {
            // peel: compute segment 0, issue its load
            ADVANCE_MERGE();
            float nxt = fminf(fminf(nxx, nxy), nxz);
            float e   = fminf(nxt, amax);
            int addr; SEG_ADDR(cur, e, addr)
            float pstep = e - cur;
            float pval  = vol[addr];
            cur = nxt;

            while (cur < end) {
                // advance to segment n+1, issue its load while load n in flight
                ADVANCE_MERGE();
                nxt = fminf(fminf(nxx, nxy), nxz);
                e   = fminf(nxt, amax);
                int addr2; SEG_ADDR(cur, e, addr2)
                float nval = vol[addr2];           // issue (vmcnt grows)
                acc = fmaf(pval, pstep, acc);      // consume load n (vmcnt(1))
                pval  = nval;
                pstep = e - cur;
                cur = nxt;
            }
            acc = fmaf(pval, pstep, acc);          // drain
        }
        #undef ADVANCE_MERGE
        #undef SEG_ADDR
    }

    // fold the block's 8 waves (each lane = one ray), then one atomic per
    // block into out[ray] (2 atomics/output total; out zeroed by memset).
    __shared__ float red[8][64];
    red[wave][lane] = acc;
    __syncthreads();

    if (wave == 0) {
        float s = red[0][lane] + red[1][lane] + red[2][lane] + red[3][lane]
                + red[4][lane] + red[5][lane] + red[6][lane] + red[7][lane];
        if (s != 0.f) {
            float rl2 = sqrtf(sdx * sdx + sdy * sdy + sdz * sdz);
            atomicAdd(&out[ti * 256 + si], s * rl2);
        }
    }
}

extern "C" void kernel_launch(void* const* d_in, const int* in_sizes, int n_in,
                              void* d_out, int out_size, void* d_ws, size_t ws_size,
                              hipStream_t stream) {
    const float* vol     = (const float*)d_in[0];
    const float* spacing = (const float*)d_in[1];
    const float* sdr     = (const float*)d_in[2];
    const float* rot     = (const float*)d_in[3];
    const float* trans   = (const float*)d_in[4];
    float* out = (float*)d_out;

    hipMemsetAsync(out, 0, (size_t)out_size * sizeof(float), stream);

    int nblocks = 2048;   // 1024 ray-groups x 2 partition-halves, 512 thr/blk
    drr_kernel<<<nblocks, 512, 0, stream>>>(vol, spacing, sdr, rot, trans, out);
}

// Round 22
// 54.656 us; speedup vs baseline: 1.0487x; 1.0487x over previous
//
#include <hip/hip_runtime.h>
#include <math.h>

// DRR via Siddon ray tracing, 256^3 volume, 256x256 detector.
// Best-measured configuration (R18, 54.4us, -44% vs baseline):
//  - 1M threads (TPR=16, ONE alpha-slice per thread): full TLP.
//  - wave = 64 CONSECUTIVE rays x ONE partition: minimal cache footprint
//    (FETCH ~39MB) and minimal divergence (adjacent rays, same partition ->
//    near-identical segment counts per lane).
//  - 512-thread blocks (8 waves): clean residency quanta.
//  - reduction: LDS fold of the block's 8 waves + 1 atomicAdd per block
//    (2 per output element, out zeroed by hipMemsetAsync).
// Inner loop: 3-way incremental Siddon merge; midpoint-trunc cells
// (bit-faithful to the reference's rounding snap for near-parallel axes);
// alpha via fmaf(i,sp,-src)*(1/sdd) (no per-plane IEEE divide);
// depth-1 software pipeline (segment n's load in flight during merge n+1).

#define NPLANE 256
constexpr int TPR = 16;

__device__ __forceinline__ float palpha(int i, float sp, float src, float rd) {
    return fmaf((float)i, sp, -src) * rd;
}

__global__ __launch_bounds__(512) void drr_kernel(
    const float* __restrict__ vol,
    const float* __restrict__ spacing,
    const float* __restrict__ sdrp,
    const float* __restrict__ rot,
    const float* __restrict__ trans,
    float* __restrict__ out)
{
    int tid  = threadIdx.x;
    int lane = tid & 63;                     // ray-in-group (fast)
    int wave = tid >> 6;                     // 0..7
    int b    = (int)blockIdx.x;
    int g    = b >> 1;                       // 64-ray group 0..1023
    int h    = b & 1;                        // partition half
    int part = (h << 3) | wave;              // 0..15
    int rl   = (g << 6) | lane;              // 0..65535 linear ray id

    // R = Rz(theta) @ Ry(phi) @ Rx(gamma): columns 0 (ray dir), 1 (u), 2 (v)
    float theta = rot[0], phi = rot[1], gam = rot[2];
    float ct = cosf(theta), st = sinf(theta);
    float cp = cosf(phi),   sp_ = sinf(phi);
    float cg = cosf(gam),   sg = sinf(gam);

    float r0x = ct * cp, r0y = st * cp, r0z = -sp_;
    float ux = ct * sp_ * sg - st * cg, uy = st * sp_ * sg + ct * cg, uz = cp * sg;
    float vx = ct * sp_ * cg + st * sg, vy = st * sp_ * cg - ct * sg, vz = cp * cg;

    // lane-fast detector axis = least stride-weighted volume motion (uniform)
    float cost_u = fabsf(ux) * 65536.f + fabsf(uy) * 256.f + fabsf(uz);
    float cost_v = fabsf(vx) * 65536.f + fabsf(vy) * 256.f + fabsf(vz);
    bool tfast = cost_u < cost_v;
    int ti = tfast ? (rl & 255) : (rl >> 8);
    int si = tfast ? (rl >> 8) : (rl & 255);

    float sdr = sdrp[0];
    float tx = trans[0], ty = trans[1], tz = trans[2];

    float sx = sdr * r0x + tx,  sy = sdr * r0y + ty,  sz = sdr * r0z + tz;
    float cxx = -sdr * r0x + tx, cxy = -sdr * r0y + ty, cxz = -sdr * r0z + tz;

    float tval = (float)(ti - 127) * 2.0f;
    float sval = (float)(si - 127) * 2.0f;

    float gx = tval * ux + sval * vx + cxx;
    float gy = tval * uy + sval * vy + cxy;
    float gz = tval * uz + sval * vz + cxz;

    float sdx = gx - sx + 1e-8f;
    float sdy = gy - sy + 1e-8f;
    float sdz = gz - sz + 1e-8f;

    float spx = spacing[0], spy = spacing[1], spz = spacing[2];
    float rdx = 1.0f / sdx, rdy = 1.0f / sdy, rdz = 1.0f / sdz;

    float a0x = palpha(0, spx, sx, rdx), a1x = palpha(NPLANE, spx, sx, rdx);
    float a0y = palpha(0, spy, sy, rdy), a1y = palpha(NPLANE, spy, sy, rdy);
    float a0z = palpha(0, spz, sz, rdz), a1z = palpha(NPLANE, spz, sz, rdz);

    float amin = fmaxf(fmaxf(fminf(a0x, a1x), fminf(a0y, a1y)), fminf(a0z, a1z));
    float amax = fminf(fminf(fmaxf(a0x, a1x), fmaxf(a0y, a1y)), fmaxf(a0z, a1z));

    float acc = 0.f;

    if (amax > amin) {
        float range = amax - amin;
        constexpr float inv = 1.0f / (float)TPR;
        float lo = fmaf(range, (float)part * inv, amin);
        float hi = (part == TPR - 1) ? INFINITY
                                     : fmaf(range, (float)(part + 1) * inv, amin);
        float end = fminf(hi, amax);

        int ix, iy, iz, dix, diy, diz;
        float nxx, nxy, nxz;

        // first plane crossing with alpha >= lo per axis
        #define SETUP(SP, SRC, SDD, RD, I, DI, NXT)                                \
        {                                                                          \
            float q = fmaf(lo, SDD, SRC) / (SP);                                   \
            q = fminf(fmaxf(q, -1.f), 257.f);                                      \
            if ((SDD) > 0.f) {                                                     \
                DI = 1;                                                            \
                I = (int)ceilf(q);                                                 \
                while (I > 0 && palpha(I - 1, SP, SRC, RD) >= lo) --I;             \
                while (I <= NPLANE && palpha(I, SP, SRC, RD) < lo) ++I;            \
                NXT = (I <= NPLANE) ? palpha(I, SP, SRC, RD) : INFINITY;           \
            } else {                                                               \
                DI = -1;                                                           \
                I = (int)floorf(q);                                                \
                while (I < NPLANE && palpha(I + 1, SP, SRC, RD) >= lo) ++I;        \
                while (I >= 0 && palpha(I, SP, SRC, RD) < lo) --I;                 \
                NXT = (I >= 0) ? palpha(I, SP, SRC, RD) : INFINITY;                \
            }                                                                      \
        }

        SETUP(spx, sx, sdx, rdx, ix, dix, nxx)
        SETUP(spy, sy, sdy, rdy, iy, diy, nxy)
        SETUP(spz, sz, sdz, rdz, iz, diz, nxz)
        #undef SETUP

        float ispx = 1.0f / spx, ispy = 1.0f / spy, ispz = 1.0f / spz;

        #define ADVANCE_MERGE()                                                    \
            if (nxx == cur) { ix += dix;                                           \
                nxx = ((unsigned)ix <= NPLANE) ? palpha(ix, spx, sx, rdx)          \
                                               : INFINITY; }                       \
            if (nxy == cur) { iy += diy;                                           \
                nxy = ((unsigned)iy <= NPLANE) ? palpha(iy, spy, sy, rdy)          \
                                               : INFINITY; }                       \
            if (nxz == cur) { iz += diz;                                           \
                nxz = ((unsigned)iz <= NPLANE) ? palpha(iz, spz, sz, rdz)          \
                                               : INFINITY; }

        #define SEG_ADDR(CUR, E, ADDR)                                             \
        {                                                                          \
            float amid = 0.5f * ((CUR) + (E));                                     \
            float pxv = fmaf(amid, sdx, sx) * ispx;                                \
            float pyv = fmaf(amid, sdy, sy) * ispy;                                \
            float pzv = fmaf(amid, sdz, sz) * ispz;                                \
            int jx = (int)pxv; jx = jx < 0 ? 0 : (jx > 255 ? 255 : jx);            \
            int jy = (int)pyv; jy = jy < 0 ? 0 : (jy > 255 ? 255 : jy);            \
            int jz = (int)pzv; jz = jz < 0 ? 0 : (jz > 255 ? 255 : jz);            \
            ADDR = (jx << 16) + (jy << 8) + jz;                                    \
        }

        float cur = fminf(fminf(nxx, nxy), nxz);

        if (cur < end) {
            // peel: compute segment 0, issue its load
            ADVANCE_MERGE();
            float nxt = fminf(fminf(nxx, nxy), nxz);
            float e   = fminf(nxt, amax);
            int addr; SEG_ADDR(cur, e, addr)
            float pstep = e - cur;
            float pval  = vol[addr];
            cur = nxt;

            while (cur < end) {
                // advance to segment n+1, issue its load while load n in flight
                ADVANCE_MERGE();
                nxt = fminf(fminf(nxx, nxy), nxz);
                e   = fminf(nxt, amax);
                int addr2; SEG_ADDR(cur, e, addr2)
                float nval = vol[addr2];           // issue (vmcnt grows)
                acc = fmaf(pval, pstep, acc);      // consume load n (vmcnt(1))
                pval  = nval;
                pstep = e - cur;
                cur = nxt;
            }
            acc = fmaf(pval, pstep, acc);          // drain
        }
        #undef ADVANCE_MERGE
        #undef SEG_ADDR
    }

    // fold the block's 8 waves (each lane = one ray), then one atomic per
    // block into out[ray] (2 atomics/output total; out zeroed by memset).
    __shared__ float red[8][64];
    red[wave][lane] = acc;
    __syncthreads();

    if (wave == 0) {
        float s = red[0][lane] + red[1][lane] + red[2][lane] + red[3][lane]
                + red[4][lane] + red[5][lane] + red[6][lane] + red[7][lane];
        if (s != 0.f) {
            float rl2 = sqrtf(sdx * sdx + sdy * sdy + sdz * sdz);
            atomicAdd(&out[ti * 256 + si], s * rl2);
        }
    }
}

extern "C" void kernel_launch(void* const* d_in, const int* in_sizes, int n_in,
                              void* d_out, int out_size, void* d_ws, size_t ws_size,
                              hipStream_t stream) {
    const float* vol     = (const float*)d_in[0];
    const float* spacing = (const float*)d_in[1];
    const float* sdr     = (const float*)d_in[2];
    const float* rot     = (const float*)d_in[3];
    const float* trans   = (const float*)d_in[4];
    float* out = (float*)d_out;

    hipMemsetAsync(out, 0, (size_t)out_size * sizeof(float), stream);

    int nblocks = 2048;   // 1024 ray-groups x 2 partition-halves, 512 thr/blk
    drr_kernel<<<nblocks, 512, 0, stream>>>(vol, spacing, sdr, rot, trans, out);
}